// Round 1
// 18927.528 us; speedup vs baseline: 1.1408x; 1.1408x over previous
//
#include <hip/hip_runtime.h>
#include <cstdint>
#include <cstddef>

// ---------------------------------------------------------------------------
// GRU persistent kernel, round 3: register-pinned weights, full-device grid.
//   - 256 blocks x 512 threads (1 block/CU on all 256 CUs), 16-col tiles
//   - every block's weight slices live PERMANENTLY in VGPRs (loaded once):
//       gate blocks: 24 x bf16x8 (96 VGPR), Y blocks: 12+8 frags
//     -> zero weight traffic in the recurrence, immune to barrier buffer_inv
//   - per phase only the activation matrix (64x3072 bf16) is read (L2-served)
//   - fence-free sc1 cross-XCD stores + 8-way distributed barrier (unchanged)
// ---------------------------------------------------------------------------

#define T_ 512
#define B_ 64
#define I_ 1024
#define H_ 2048
#define NB 256
#define NTHREADS 512
#define GSTRIDE (NB * NTHREADS)

typedef __attribute__((ext_vector_type(8))) __bf16 bf16x8;
typedef __attribute__((ext_vector_type(2))) __bf16 bf16x2;
typedef __attribute__((ext_vector_type(4))) float f32x4;
typedef __attribute__((ext_vector_type(2))) float f32x2;

// ---- workspace layout (bytes) ----
static constexpr size_t OFF_BAR  = 0;                      // 8 counters x 64B
static constexpr size_t OFF_WXZT = 1024;
static constexpr size_t SZ_WXT   = (size_t)H_ * I_ * 2;    // 4 MiB
static constexpr size_t SZ_WHT   = (size_t)H_ * H_ * 2;    // 8 MiB
static constexpr size_t OFF_WXRT = OFF_WXZT + SZ_WXT;
static constexpr size_t OFF_WXHT = OFF_WXRT + SZ_WXT;
static constexpr size_t OFF_WHZT = OFF_WXHT + SZ_WXT;
static constexpr size_t OFF_WHRT = OFF_WHZT + SZ_WHT;
static constexpr size_t OFF_WHHT = OFF_WHRT + SZ_WHT;
static constexpr size_t OFF_WHQT = OFF_WHHT + SZ_WHT;      // N=1024,K=2048
static constexpr size_t OFF_XBF  = OFF_WHQT + SZ_WXT;
static constexpr size_t OFF_HBF  = OFF_XBF + (size_t)2 * B_ * I_ * 2;
static constexpr size_t OFF_RHBF = OFF_HBF + (size_t)2 * B_ * H_ * 2;
static constexpr size_t WS_NEEDED = OFF_RHBF + (size_t)B_ * H_ * 2;

__device__ __forceinline__ float fsigmoid(float x) { return 1.0f / (1.0f + __expf(-x)); }
__device__ __forceinline__ float ftanh(float x)    { return 2.0f / (1.0f + __expf(-2.0f * x)) - 1.0f; }

// ---- coherent (sc1 write-through) stores for cross-block data ----
__device__ __forceinline__ void cstore8(void* p, unsigned long long v) {
    __hip_atomic_store((unsigned long long*)p, v, __ATOMIC_RELAXED, __HIP_MEMORY_SCOPE_AGENT);
}
__device__ __forceinline__ void cstore4(void* p, unsigned v) {
    __hip_atomic_store((unsigned*)p, v, __ATOMIC_RELAXED, __HIP_MEMORY_SCOPE_AGENT);
}
__device__ __forceinline__ unsigned long long pack4bf(float a, float b, float c, float d) {
    union { unsigned short s[4]; unsigned long long u; } x;
    union { __bf16 b; unsigned short s; } t;
    t.b = (__bf16)a; x.s[0] = t.s;
    t.b = (__bf16)b; x.s[1] = t.s;
    t.b = (__bf16)c; x.s[2] = t.s;
    t.b = (__bf16)d; x.s[3] = t.s;
    return x.u;
}
__device__ __forceinline__ unsigned pack2bf(float a, float b) {
    union { unsigned short s[2]; unsigned u; } x;
    union { __bf16 b; unsigned short s; } t;
    t.b = (__bf16)a; x.s[0] = t.s;
    t.b = (__bf16)b; x.s[1] = t.s;
    return x.u;
}

// ---- fence-free grid barrier (unchanged semantics from round 2) ----
__device__ __forceinline__ void grid_sync(unsigned* bars, unsigned& target) {
    __syncthreads();
    target += (unsigned)NB;
    if (threadIdx.x == 0) {
        __hip_atomic_fetch_add(&bars[(blockIdx.x & 7) * 16], 1u,
                               __ATOMIC_RELAXED, __HIP_MEMORY_SCOPE_AGENT);
        for (;;) {
            unsigned sum = 0;
#pragma unroll
            for (int g = 0; g < 8; ++g)
                sum += __hip_atomic_load(&bars[g * 16],
                                         __ATOMIC_RELAXED, __HIP_MEMORY_SCOPE_AGENT);
            if (sum >= target) break;
            __builtin_amdgcn_s_sleep(2);
        }
        (void)__hip_atomic_load(&bars[0], __ATOMIC_ACQUIRE, __HIP_MEMORY_SCOPE_AGENT);
    }
    __syncthreads();
    asm volatile("" ::: "memory");
}

// prologue-only barrier: full fence (weight transpose uses normal cached
// stores; one-time wbl2 makes them globally visible)
__device__ __forceinline__ void grid_sync_full(unsigned* bars, unsigned& target) {
    __syncthreads();
    __threadfence();
    target += (unsigned)NB;
    if (threadIdx.x == 0) {
        __hip_atomic_fetch_add(&bars[(blockIdx.x & 7) * 16], 1u,
                               __ATOMIC_RELAXED, __HIP_MEMORY_SCOPE_AGENT);
        for (;;) {
            unsigned sum = 0;
#pragma unroll
            for (int g = 0; g < 8; ++g)
                sum += __hip_atomic_load(&bars[g * 16],
                                         __ATOMIC_RELAXED, __HIP_MEMORY_SCOPE_AGENT);
            if (sum >= target) break;
            __builtin_amdgcn_s_sleep(2);
        }
        (void)__hip_atomic_load(&bars[0], __ATOMIC_ACQUIRE, __HIP_MEMORY_SCOPE_AGENT);
    }
    __syncthreads();
    asm volatile("" ::: "memory");
}

// f32 (K x N row-major) -> bf16 transposed (N x K row-major), normal stores
__device__ __forceinline__ void transpose_cvt(const float* __restrict__ src,
                                              __bf16* __restrict__ dst,
                                              int K, int lgN) {
    const int N = 1 << lgN;
    const int total = K << lgN;
    for (int idx = (int)(blockIdx.x * blockDim.x + threadIdx.x); idx < total; idx += GSTRIDE) {
        int k = idx >> lgN;
        int n = idx & (N - 1);
        dst[(size_t)n * K + k] = (__bf16)src[idx];
    }
}

// ---------------------------------------------------------------------------
// Block GEMM with REGISTER-RESIDENT B. Tile = 64 rows x 16 cols.
// K split 8 ways across waves; wave w, iteration i covers k-block
//   i <  IX : X-part, kb = (w + i*8)*32        (K-stride I_)
//   i >= IX : H-part, kb = (w + (i-IX)*8)*32   (K-stride H_)
// pbw[i] is the matching pre-loaded weight fragment (cols c..c+15).
// 3-deep software pipeline on the A-fragments only (weights cost nothing).
// Output: out2[j] = C[row = tid>>3][col = ((tid&7)*2) + j]  (local cols).
// ---------------------------------------------------------------------------
template<int IX, int IH, int N>
__device__ __forceinline__ void gemm_reg(
    const __bf16* __restrict__ Ax, const __bf16* __restrict__ Ah,
    const bf16x8 (&pbw)[N], float* __restrict__ red, float out2[2])
{
    constexpr int ITER = IX + IH;
    constexpr int PIPE = 3;
    constexpr int RP   = 20;               // padded pitch: <=2-way bank alias
    static_assert(ITER <= N, "weight frags");
    const int tid  = (int)threadIdx.x;
    const int lane = tid & 63;
    const int w    = tid >> 6;
    const int l15  = lane & 15;
    const int q8   = (lane >> 4) << 3;     // k offset of this quad
    const int q4   = (lane >> 4) << 2;     // row offset (C/D layout)

    f32x4 acc[4];
#pragma unroll
    for (int m = 0; m < 4; ++m) acc[m] = f32x4{0.f, 0.f, 0.f, 0.f};

    bf16x8 pa[PIPE][4];
    auto lseg = [&](int i, int s) {
        const bool isx = (i < IX);
        const __bf16* A = isx ? Ax : Ah;
        const int ks = isx ? I_ : H_;
        const int kb = (isx ? ((w + (i << 3)) << 5)
                            : ((w + ((i - IX) << 3)) << 5)) + q8;
#pragma unroll
        for (int m = 0; m < 4; ++m)
            pa[s][m] = *(const bf16x8*)(A + (size_t)((m << 4) + l15) * ks + kb);
    };

    lseg(0, 0);
    if constexpr (ITER > 1) lseg(1, 1);
    if constexpr (ITER > 2) lseg(2, 2);
#pragma unroll
    for (int i = 0; i < ITER; ++i) {
        const int s = i % PIPE;
#pragma unroll
        for (int m = 0; m < 4; ++m)
            acc[m] = __builtin_amdgcn_mfma_f32_16x16x32_bf16(pa[s][m], pbw[i], acc[m], 0, 0, 0);
        if (i + PIPE < ITER) lseg(i + PIPE, s);
    }

    // cross-wave reduction through LDS (64x16 tile, pitch 20)
    if (w >= 4) {
        float* rw = red + (size_t)(w - 4) * (64 * RP);
#pragma unroll
        for (int m = 0; m < 4; ++m)
#pragma unroll
            for (int r = 0; r < 4; ++r)
                rw[((m << 4) + q4 + r) * RP + l15] = acc[m][r];
    }
    __syncthreads();
    if (w < 4) {
        float* rw = red + (size_t)w * (64 * RP);
#pragma unroll
        for (int m = 0; m < 4; ++m)
#pragma unroll
            for (int r = 0; r < 4; ++r)
                rw[((m << 4) + q4 + r) * RP + l15] += acc[m][r];
    }
    __syncthreads();
    {
        const int a = (tid >> 3) * RP + ((tid & 7) << 1);
        f32x2 s0 = *(const f32x2*)(red + a);
        f32x2 s1 = *(const f32x2*)(red + 64 * RP + a);
        f32x2 s2 = *(const f32x2*)(red + 2 * 64 * RP + a);
        f32x2 s3 = *(const f32x2*)(red + 3 * 64 * RP + a);
        f32x2 s = s0 + s1 + s2 + s3;
        out2[0] = s[0]; out2[1] = s[1];
    }
}

__global__ __launch_bounds__(NTHREADS, 1) void gru_persistent(
    const float* __restrict__ inputs, const float* __restrict__ state,
    const float* __restrict__ Wxz, const float* __restrict__ Whz, const float* __restrict__ bz,
    const float* __restrict__ Wxr, const float* __restrict__ Whr, const float* __restrict__ br,
    const float* __restrict__ Wxh, const float* __restrict__ Whh, const float* __restrict__ bh,
    const float* __restrict__ Whq, const float* __restrict__ bhq,
    float* __restrict__ out, char* __restrict__ ws) {

    unsigned* bars = (unsigned*)(ws + OFF_BAR);
    __bf16* WxzT = (__bf16*)(ws + OFF_WXZT);
    __bf16* WxrT = (__bf16*)(ws + OFF_WXRT);
    __bf16* WxhT = (__bf16*)(ws + OFF_WXHT);
    __bf16* WhzT = (__bf16*)(ws + OFF_WHZT);
    __bf16* WhrT = (__bf16*)(ws + OFF_WHRT);
    __bf16* WhhT = (__bf16*)(ws + OFF_WHHT);
    __bf16* WhqT = (__bf16*)(ws + OFF_WHQT);
    __bf16* Xbf  = (__bf16*)(ws + OFF_XBF);   // 2 x (64 x 1024)
    __bf16* Hbf  = (__bf16*)(ws + OFF_HBF);   // 2 x (64 x 2048)
    __bf16* RHbf = (__bf16*)(ws + OFF_RHBF);  // 64 x 2048

    __shared__ float red[4 * 64 * 20];        // 20 KB reduction scratch

    const int b   = (int)blockIdx.x;
    const int tid = (int)threadIdx.x;
    const int c16 = (b & 127) << 4;           // col base (Z cols for b<128, R cols else)
    const int gr  = tid >> 3;                 // output row this thread owns
    const int gc  = (tid & 7) << 1;           // output col (2 consecutive)
    unsigned bar_target = 0;

    // ---------------- prologue ---------------------------------------------
    transpose_cvt(Wxz, WxzT, I_, 11);
    transpose_cvt(Wxr, WxrT, I_, 11);
    transpose_cvt(Wxh, WxhT, I_, 11);
    transpose_cvt(Whz, WhzT, H_, 11);
    transpose_cvt(Whr, WhrT, H_, 11);
    transpose_cvt(Whh, WhhT, H_, 11);
    transpose_cvt(Whq, WhqT, H_, 10);
    {
        int q = b * NTHREADS + tid;           // quad index
        if (q < B_ * I_ / 4) {
            f32x4 v = *(const f32x4*)(inputs + (size_t)q * 4);
            cstore8(Xbf + (size_t)q * 4, pack4bf(v[0], v[1], v[2], v[3]));
        }
        if (q < B_ * H_ / 4) {
            f32x4 v = *(const f32x4*)(state + (size_t)q * 4);
            cstore8(Hbf + (size_t)q * 4, pack4bf(v[0], v[1], v[2], v[3]));
        }
    }

    // register-resident H (f32) and Z for the 2 cols x row this thread owns
    float hreg[2] = {0.f, 0.f};
    float zreg[2] = {0.f, 0.f};
    if (b < 128) {
        f32x2 v = *(const f32x2*)(state + (size_t)gr * H_ + c16 + gc);
        hreg[0] = v[0]; hreg[1] = v[1];
    }
    grid_sync_full(bars, bar_target);

    // ---------------- pin weight slices in registers (once) ----------------
    const int lane = tid & 63;
    const int w    = tid >> 6;
    const int l15  = lane & 15;
    const int q8   = (lane >> 4) << 3;

    bf16x8 pbA[12];   // phase-A weights: Wxz|Whz (b<128) or Wxr|Whr (b>=128)
    bf16x8 pbB[12];   // phase-B weights: Wxh|Whh (b<128) or Whq[0..7] (128<=b<192)
    if (b < 128) {
#pragma unroll
        for (int i = 0; i < 4; ++i)
            pbA[i] = *(const bf16x8*)(WxzT + (size_t)(c16 + l15) * I_ + ((w + (i << 3)) << 5) + q8);
#pragma unroll
        for (int i = 0; i < 8; ++i)
            pbA[4 + i] = *(const bf16x8*)(WhzT + (size_t)(c16 + l15) * H_ + ((w + (i << 3)) << 5) + q8);
#pragma unroll
        for (int i = 0; i < 4; ++i)
            pbB[i] = *(const bf16x8*)(WxhT + (size_t)(c16 + l15) * I_ + ((w + (i << 3)) << 5) + q8);
#pragma unroll
        for (int i = 0; i < 8; ++i)
            pbB[4 + i] = *(const bf16x8*)(WhhT + (size_t)(c16 + l15) * H_ + ((w + (i << 3)) << 5) + q8);
    } else {
#pragma unroll
        for (int i = 0; i < 4; ++i)
            pbA[i] = *(const bf16x8*)(WxrT + (size_t)(c16 + l15) * I_ + ((w + (i << 3)) << 5) + q8);
#pragma unroll
        for (int i = 0; i < 8; ++i)
            pbA[4 + i] = *(const bf16x8*)(WhrT + (size_t)(c16 + l15) * H_ + ((w + (i << 3)) << 5) + q8);
        if (b < 192) {
            const int yc = (b - 128) << 4;
#pragma unroll
            for (int i = 0; i < 8; ++i)
                pbB[i] = *(const bf16x8*)(WhqT + (size_t)(yc + l15) * H_ + ((w + (i << 3)) << 5) + q8);
        }
    }

    // ---------------- main recurrence --------------------------------------
    for (int t = 0; t < T_; ++t) {
        const int cur = t & 1, nxt = cur ^ 1;
        const __bf16* Xc = Xbf + (size_t)cur * B_ * I_;
        const __bf16* Hc = Hbf + (size_t)cur * B_ * H_;
        float o2[2];

        // ---- phase A: Z (blocks 0..127) / R,RH (blocks 128..255) ----
        if (b < 128) {
            gemm_reg<4, 8>(Xc, Hc, pbA, red, o2);
            zreg[0] = fsigmoid(o2[0] + bz[c16 + gc]);
            zreg[1] = fsigmoid(o2[1] + bz[c16 + gc + 1]);
        } else {
            gemm_reg<4, 8>(Xc, Hc, pbA, red, o2);
            bf16x2 h2 = *(const bf16x2*)(Hc + (size_t)gr * H_ + c16 + gc);
            float rh0 = fsigmoid(o2[0] + br[c16 + gc])     * (float)h2[0];
            float rh1 = fsigmoid(o2[1] + br[c16 + gc + 1]) * (float)h2[1];
            cstore4(RHbf + (size_t)gr * H_ + c16 + gc, pack2bf(rh0, rh1));
        }
        grid_sync(bars, bar_target);

        // ---- phase B: H~/H_new | Y_{t-1} | X_{t+1} conversion ----
        if (b < 128) {
            gemm_reg<4, 8>(Xc, RHbf, pbB, red, o2);
            float ht0 = ftanh(o2[0] + bh[c16 + gc]);
            float ht1 = ftanh(o2[1] + bh[c16 + gc + 1]);
            float hn0 = zreg[0] * hreg[0] + (1.0f - zreg[0]) * ht0;
            float hn1 = zreg[1] * hreg[1] + (1.0f - zreg[1]) * ht1;
            hreg[0] = hn0; hreg[1] = hn1;
            cstore4(Hbf + (size_t)nxt * B_ * H_ + (size_t)gr * H_ + c16 + gc,
                    pack2bf(hn0, hn1));
            if (t == T_ - 1) {
                f32x2 v; v[0] = hn0; v[1] = hn1;
                *(f32x2*)(out + (size_t)T_ * B_ * I_ + (size_t)gr * H_ + c16 + gc) = v;
            }
        } else if (b < 192) {
            if (t > 0) {
                const int yc = (b - 128) << 4;
                gemm_reg<0, 8>(nullptr, Hc, pbB, red, o2);
                f32x2 v;
                v[0] = o2[0] + bhq[yc + gc];
                v[1] = o2[1] + bhq[yc + gc + 1];
                *(f32x2*)(out + ((size_t)(t - 1) * B_ + gr) * I_ + yc + gc) = v;
            }
        } else {
            if (t + 1 < T_ && tid < 256) {
                const int idx = (((b - 192) << 8) + tid) << 2;
                f32x4 v = *(const f32x4*)(inputs + (size_t)(t + 1) * B_ * I_ + idx);
                cstore8(Xbf + (size_t)nxt * B_ * I_ + idx,
                        pack4bf(v[0], v[1], v[2], v[3]));
            }
        }
        grid_sync(bars, bar_target);
    }

    // ---------------- epilogue: Y_{T-1} ------------------------------------
    if (b >= 128 && b < 192) {
        const __bf16* Hc = Hbf;   // slot (T_ & 1) == 0
        const int yc = (b - 128) << 4;
        float o2[2];
        gemm_reg<0, 8>(nullptr, Hc, pbB, red, o2);
        f32x2 v;
        v[0] = o2[0] + bhq[yc + gc];
        v[1] = o2[1] + bhq[yc + gc + 1];
        *(f32x2*)(out + ((size_t)(T_ - 1) * B_ + gr) * I_ + yc + gc) = v;
    }
}

extern "C" void kernel_launch(void* const* d_in, const int* in_sizes, int n_in,
                              void* d_out, int out_size, void* d_ws, size_t ws_size,
                              hipStream_t stream) {
    if (ws_size < WS_NEEDED) return;  // ~41.5 MB scratch required

    const float* inputs = (const float*)d_in[0];
    const float* state  = (const float*)d_in[1];
    const float* Wxz    = (const float*)d_in[2];
    const float* Whz    = (const float*)d_in[3];
    const float* bz     = (const float*)d_in[4];
    const float* Wxr    = (const float*)d_in[5];
    const float* Whr    = (const float*)d_in[6];
    const float* br     = (const float*)d_in[7];
    const float* Wxh    = (const float*)d_in[8];
    const float* Whh    = (const float*)d_in[9];
    const float* bh     = (const float*)d_in[10];
    const float* Whq    = (const float*)d_in[11];
    const float* bhq    = (const float*)d_in[12];

    hipMemsetAsync(d_ws, 0, 1024, stream);  // barrier counters
    gru_persistent<<<NB, NTHREADS, 0, stream>>>(
        inputs, state, Wxz, Whz, bz, Wxr, Whr, br, Wxh, Whh, bh, Whq, bhq,
        (float*)d_out, (char*)d_ws);
}

// Round 3
// 16270.663 us; speedup vs baseline: 1.3271x; 1.1633x over previous
//
#include <hip/hip_runtime.h>
#include <cstdint>
#include <cstddef>

// ---------------------------------------------------------------------------
// GRU persistent kernel, round 5: single-detector broadcast barrier.
//   - round 4's relay/mailbox scheme (hwreg XCC_ID + sc0 asm + WB-store
//     visibility assumptions) killed the container; ALL of it is removed.
//   - barrier now: 256 arrivals via relaxed agent fetch_add on 16 spread
//     lines; ONE detector block (255) polls them; detector broadcasts the
//     epoch on a dedicated line; 255 blocks poll only that line (pure
//     read-shared, no RMW-vs-read contention). Fallback: pollers cross-check
//     the arrival sum every 2048 spins (degrades to round-3 speed, never
//     hangs).
//   - weights stay register-pinned; barrier-1 arrive/wait split overlap kept
//     (X-part of H~ GEMM, whole Y GEMM, X-conversion inside the wait).
// ---------------------------------------------------------------------------

#define T_ 512
#define B_ 64
#define I_ 1024
#define H_ 2048
#define NB 256
#define NTHREADS 512
#define GSTRIDE (NB * NTHREADS)

typedef __attribute__((ext_vector_type(8))) __bf16 bf16x8;
typedef __attribute__((ext_vector_type(2))) __bf16 bf16x2;
typedef __attribute__((ext_vector_type(4))) float f32x4;
typedef __attribute__((ext_vector_type(2))) float f32x2;

// ---- workspace layout (bytes) ----
// barrier region: arr = 16 counters x 64B [0..1023]; epoch word @1024.
static constexpr size_t OFF_BAR  = 0;
static constexpr size_t OFF_WXZT = 3072;
static constexpr size_t SZ_WXT   = (size_t)H_ * I_ * 2;    // 4 MiB
static constexpr size_t SZ_WHT   = (size_t)H_ * H_ * 2;    // 8 MiB
static constexpr size_t OFF_WXRT = OFF_WXZT + SZ_WXT;
static constexpr size_t OFF_WXHT = OFF_WXRT + SZ_WXT;
static constexpr size_t OFF_WHZT = OFF_WXHT + SZ_WXT;
static constexpr size_t OFF_WHRT = OFF_WHZT + SZ_WHT;
static constexpr size_t OFF_WHHT = OFF_WHRT + SZ_WHT;
static constexpr size_t OFF_WHQT = OFF_WHHT + SZ_WHT;      // N=1024,K=2048
static constexpr size_t OFF_XBF  = OFF_WHQT + SZ_WXT;
static constexpr size_t OFF_HBF  = OFF_XBF + (size_t)2 * B_ * I_ * 2;
static constexpr size_t OFF_RHBF = OFF_HBF + (size_t)2 * B_ * H_ * 2;
static constexpr size_t WS_NEEDED = OFF_RHBF + (size_t)B_ * H_ * 2;

__device__ __forceinline__ float fsigmoid(float x) { return 1.0f / (1.0f + __expf(-x)); }
__device__ __forceinline__ float ftanh(float x)    { return 2.0f / (1.0f + __expf(-2.0f * x)) - 1.0f; }

// ---- coherent (sc1 write-through) stores for cross-block data ----
__device__ __forceinline__ void cstore8(void* p, unsigned long long v) {
    __hip_atomic_store((unsigned long long*)p, v, __ATOMIC_RELAXED, __HIP_MEMORY_SCOPE_AGENT);
}
__device__ __forceinline__ void cstore4(void* p, unsigned v) {
    __hip_atomic_store((unsigned*)p, v, __ATOMIC_RELAXED, __HIP_MEMORY_SCOPE_AGENT);
}
__device__ __forceinline__ unsigned long long pack4bf(float a, float b, float c, float d) {
    union { unsigned short s[4]; unsigned long long u; } x;
    union { __bf16 b; unsigned short s; } t;
    t.b = (__bf16)a; x.s[0] = t.s;
    t.b = (__bf16)b; x.s[1] = t.s;
    t.b = (__bf16)c; x.s[2] = t.s;
    t.b = (__bf16)d; x.s[3] = t.s;
    return x.u;
}
__device__ __forceinline__ unsigned pack2bf(float a, float b) {
    union { unsigned short s[2]; unsigned u; } x;
    union { __bf16 b; unsigned short s; } t;
    t.b = (__bf16)a; x.s[0] = t.s;
    t.b = (__bf16)b; x.s[1] = t.s;
    return x.u;
}

// ---- barrier: arrive ------------------------------------------------------
__device__ __forceinline__ void bar_arrive(unsigned* arr) {
    __syncthreads();   // drains vmcnt -> this block's WT stores are globally visible
    if (threadIdx.x == 0)
        __hip_atomic_fetch_add(&arr[(blockIdx.x & 15) * 16], 1u,
                               __ATOMIC_RELAXED, __HIP_MEMORY_SCOPE_AGENT);
}

__device__ __forceinline__ void bar_arrive_fence(unsigned* arr) {
    __syncthreads();
    __threadfence();   // prologue only: flush write-back transpose stores
    if (threadIdx.x == 0)
        __hip_atomic_fetch_add(&arr[(blockIdx.x & 15) * 16], 1u,
                               __ATOMIC_RELAXED, __HIP_MEMORY_SCOPE_AGENT);
}

__device__ __forceinline__ unsigned arr_sum(unsigned* arr) {
    unsigned sum = 0;
#pragma unroll
    for (int g = 0; g < 16; ++g)
        sum += __hip_atomic_load(&arr[g * 16],
                                 __ATOMIC_RELAXED, __HIP_MEMORY_SCOPE_AGENT);
    return sum;
}

// ---- barrier: wait (detector broadcast) -----------------------------------
__device__ __forceinline__ void bar_wait(unsigned* arr, unsigned* epw, unsigned ep) {
    if (threadIdx.x == 0) {
        const unsigned want = ep * (unsigned)NB;
        if (blockIdx.x == NB - 1) {
            // sole poller of the arrival counters
            while (arr_sum(arr) < want)
                __builtin_amdgcn_s_sleep(1);
            __hip_atomic_store(epw, ep, __ATOMIC_RELAXED, __HIP_MEMORY_SCOPE_AGENT);
        } else {
            // read-only poll on one dedicated LLC line
            int spins = 0;
            for (;;) {
                if (__hip_atomic_load(epw, __ATOMIC_RELAXED,
                                      __HIP_MEMORY_SCOPE_AGENT) >= ep) break;
                if ((++spins & 2047) == 0 && arr_sum(arr) >= want) break;  // insurance
                __builtin_amdgcn_s_sleep(1);
            }
        }
        // acquire: one cache-inv so subsequent normal loads see fresh data
        (void)__hip_atomic_load(&arr[0], __ATOMIC_ACQUIRE, __HIP_MEMORY_SCOPE_AGENT);
    }
    __syncthreads();
    asm volatile("" ::: "memory");
}

// f32 (K x N row-major) -> bf16 transposed (N x K row-major), normal stores
__device__ __forceinline__ void transpose_cvt(const float* __restrict__ src,
                                              __bf16* __restrict__ dst,
                                              int K, int lgN) {
    const int N = 1 << lgN;
    const int total = K << lgN;
    for (int idx = (int)(blockIdx.x * blockDim.x + threadIdx.x); idx < total; idx += GSTRIDE) {
        int k = idx >> lgN;
        int n = idx & (N - 1);
        dst[(size_t)n * K + k] = (__bf16)src[idx];
    }
}

// ---------------------------------------------------------------------------
// GEMM pieces with REGISTER-RESIDENT B. Tile = 64 rows x 16 cols.
// Wave w, segment i covers kb = (w + i*8)*32 within A's K dim (stride ks).
// pbw[OFF+i] is the matching pinned weight fragment.
// ---------------------------------------------------------------------------
template<int NSEG, int OFF, int N>
__device__ __forceinline__ void gemm_accN(const __bf16* __restrict__ A, int ks,
                                          const bf16x8 (&pbw)[N], f32x4 acc[4]) {
    static_assert(OFF + NSEG <= N, "weight frags");
    const int tid  = (int)threadIdx.x;
    const int lane = tid & 63;
    const int w    = tid >> 6;
    const int l15  = lane & 15;
    const int q8   = (lane >> 4) << 3;

    bf16x8 pa[3][4];
    auto lseg = [&](int i, int s) {
        const int kb = ((w + (i << 3)) << 5) + q8;
#pragma unroll
        for (int m = 0; m < 4; ++m)
            pa[s][m] = *(const bf16x8*)(A + (size_t)((m << 4) + l15) * ks + kb);
    };

    lseg(0, 0);
    if constexpr (NSEG > 1) lseg(1, 1);
    if constexpr (NSEG > 2) lseg(2, 2);
#pragma unroll
    for (int i = 0; i < NSEG; ++i) {
        const int s = i % 3;
#pragma unroll
        for (int m = 0; m < 4; ++m)
            acc[m] = __builtin_amdgcn_mfma_f32_16x16x32_bf16(pa[s][m], pbw[OFF + i], acc[m], 0, 0, 0);
        if (i + 3 < NSEG) lseg(i + 3, s);
    }
}

// cross-wave reduction through LDS (64x16 tile, pitch 20)
__device__ __forceinline__ void gemm_reduce(f32x4 acc[4], float* __restrict__ red,
                                            float out2[2]) {
    constexpr int RP = 20;
    const int tid  = (int)threadIdx.x;
    const int lane = tid & 63;
    const int w    = tid >> 6;
    const int l15  = lane & 15;
    const int q4   = (lane >> 4) << 2;

    if (w >= 4) {
        float* rw = red + (size_t)(w - 4) * (64 * RP);
#pragma unroll
        for (int m = 0; m < 4; ++m)
#pragma unroll
            for (int r = 0; r < 4; ++r)
                rw[((m << 4) + q4 + r) * RP + l15] = acc[m][r];
    }
    __syncthreads();
    if (w < 4) {
        float* rw = red + (size_t)w * (64 * RP);
#pragma unroll
        for (int m = 0; m < 4; ++m)
#pragma unroll
            for (int r = 0; r < 4; ++r)
                rw[((m << 4) + q4 + r) * RP + l15] += acc[m][r];
    }
    __syncthreads();
    {
        const int a = (tid >> 3) * RP + ((tid & 7) << 1);
        f32x2 s0 = *(const f32x2*)(red + a);
        f32x2 s1 = *(const f32x2*)(red + 64 * RP + a);
        f32x2 s2 = *(const f32x2*)(red + 2 * 64 * RP + a);
        f32x2 s3 = *(const f32x2*)(red + 3 * 64 * RP + a);
        f32x2 s = s0 + s1 + s2 + s3;
        out2[0] = s[0]; out2[1] = s[1];
    }
}

// combined 12-segment pipeline for phase A (X then H without drain)
template<int IX, int IH, int N>
__device__ __forceinline__ void gemm_reg(
    const __bf16* __restrict__ Ax, const __bf16* __restrict__ Ah,
    const bf16x8 (&pbw)[N], float* __restrict__ red, float out2[2])
{
    constexpr int ITER = IX + IH;
    static_assert(ITER <= N, "weight frags");
    const int tid  = (int)threadIdx.x;
    const int lane = tid & 63;
    const int w    = tid >> 6;
    const int l15  = lane & 15;
    const int q8   = (lane >> 4) << 3;

    f32x4 acc[4];
#pragma unroll
    for (int m = 0; m < 4; ++m) acc[m] = f32x4{0.f, 0.f, 0.f, 0.f};

    bf16x8 pa[3][4];
    auto lseg = [&](int i, int s) {
        const bool isx = (i < IX);
        const __bf16* A = isx ? Ax : Ah;
        const int ks = isx ? I_ : H_;
        const int kb = (isx ? ((w + (i << 3)) << 5)
                            : ((w + ((i - IX) << 3)) << 5)) + q8;
#pragma unroll
        for (int m = 0; m < 4; ++m)
            pa[s][m] = *(const bf16x8*)(A + (size_t)((m << 4) + l15) * ks + kb);
    };

    lseg(0, 0);
    if constexpr (ITER > 1) lseg(1, 1);
    if constexpr (ITER > 2) lseg(2, 2);
#pragma unroll
    for (int i = 0; i < ITER; ++i) {
        const int s = i % 3;
#pragma unroll
        for (int m = 0; m < 4; ++m)
            acc[m] = __builtin_amdgcn_mfma_f32_16x16x32_bf16(pa[s][m], pbw[i], acc[m], 0, 0, 0);
        if (i + 3 < ITER) lseg(i + 3, s);
    }
    gemm_reduce(acc, red, out2);
}

__global__ __launch_bounds__(NTHREADS, 1) void gru_persistent(
    const float* __restrict__ inputs, const float* __restrict__ state,
    const float* __restrict__ Wxz, const float* __restrict__ Whz, const float* __restrict__ bz,
    const float* __restrict__ Wxr, const float* __restrict__ Whr, const float* __restrict__ br,
    const float* __restrict__ Wxh, const float* __restrict__ Whh, const float* __restrict__ bh,
    const float* __restrict__ Whq, const float* __restrict__ bhq,
    float* __restrict__ out, char* __restrict__ ws) {

    unsigned* arr = (unsigned*)(ws + OFF_BAR);          // 16 x 64B
    unsigned* epw = (unsigned*)(ws + OFF_BAR + 1024);   // epoch broadcast word
    __bf16* WxzT = (__bf16*)(ws + OFF_WXZT);
    __bf16* WxrT = (__bf16*)(ws + OFF_WXRT);
    __bf16* WxhT = (__bf16*)(ws + OFF_WXHT);
    __bf16* WhzT = (__bf16*)(ws + OFF_WHZT);
    __bf16* WhrT = (__bf16*)(ws + OFF_WHRT);
    __bf16* WhhT = (__bf16*)(ws + OFF_WHHT);
    __bf16* WhqT = (__bf16*)(ws + OFF_WHQT);
    __bf16* Xbf  = (__bf16*)(ws + OFF_XBF);   // 2 x (64 x 1024)
    __bf16* Hbf  = (__bf16*)(ws + OFF_HBF);   // 2 x (64 x 2048)
    __bf16* RHbf = (__bf16*)(ws + OFF_RHBF);  // 64 x 2048

    __shared__ float red[4 * 64 * 20];        // 20 KB reduction scratch

    const int b   = (int)blockIdx.x;
    const int tid = (int)threadIdx.x;
    const int c16 = (b & 127) << 4;           // col base (Z cols b<128, R cols else)
    const int gr  = tid >> 3;                 // output row this thread owns
    const int gc  = (tid & 7) << 1;           // output col (2 consecutive)
    unsigned ep = 0;

    // ---------------- prologue ---------------------------------------------
    transpose_cvt(Wxz, WxzT, I_, 11);
    transpose_cvt(Wxr, WxrT, I_, 11);
    transpose_cvt(Wxh, WxhT, I_, 11);
    transpose_cvt(Whz, WhzT, H_, 11);
    transpose_cvt(Whr, WhrT, H_, 11);
    transpose_cvt(Whh, WhhT, H_, 11);
    transpose_cvt(Whq, WhqT, H_, 10);
    {
        int q = b * NTHREADS + tid;           // quad index
        if (q < B_ * I_ / 4) {
            f32x4 v = *(const f32x4*)(inputs + (size_t)q * 4);
            cstore8(Xbf + (size_t)q * 4, pack4bf(v[0], v[1], v[2], v[3]));
        }
        if (q < B_ * H_ / 4) {
            f32x4 v = *(const f32x4*)(state + (size_t)q * 4);
            cstore8(Hbf + (size_t)q * 4, pack4bf(v[0], v[1], v[2], v[3]));
        }
    }

    // register-resident H (f32) and Z for the 2 cols x row this thread owns
    float hreg[2] = {0.f, 0.f};
    float zreg[2] = {0.f, 0.f};
    if (b < 128) {
        f32x2 v = *(const f32x2*)(state + (size_t)gr * H_ + c16 + gc);
        hreg[0] = v[0]; hreg[1] = v[1];
    }
    bar_arrive_fence(arr);
    bar_wait(arr, epw, ++ep);

    // ---------------- pin weight slices in registers (once) ----------------
    const int lane = tid & 63;
    const int w    = tid >> 6;
    const int l15  = lane & 15;
    const int q8   = (lane >> 4) << 3;

    bf16x8 pbA[12];   // phase-A weights: Wxz|Whz (b<128) or Wxr|Whr (b>=128)
    bf16x8 pbB[12];   // phase-B weights: Wxh|Whh (b<128) or Whq[0..7] (128<=b<192)
    if (b < 128) {
#pragma unroll
        for (int i = 0; i < 4; ++i)
            pbA[i] = *(const bf16x8*)(WxzT + (size_t)(c16 + l15) * I_ + ((w + (i << 3)) << 5) + q8);
#pragma unroll
        for (int i = 0; i < 8; ++i)
            pbA[4 + i] = *(const bf16x8*)(WhzT + (size_t)(c16 + l15) * H_ + ((w + (i << 3)) << 5) + q8);
#pragma unroll
        for (int i = 0; i < 4; ++i)
            pbB[i] = *(const bf16x8*)(WxhT + (size_t)(c16 + l15) * I_ + ((w + (i << 3)) << 5) + q8);
#pragma unroll
        for (int i = 0; i < 8; ++i)
            pbB[4 + i] = *(const bf16x8*)(WhhT + (size_t)(c16 + l15) * H_ + ((w + (i << 3)) << 5) + q8);
    } else {
#pragma unroll
        for (int i = 0; i < 4; ++i)
            pbA[i] = *(const bf16x8*)(WxrT + (size_t)(c16 + l15) * I_ + ((w + (i << 3)) << 5) + q8);
#pragma unroll
        for (int i = 0; i < 8; ++i)
            pbA[4 + i] = *(const bf16x8*)(WhrT + (size_t)(c16 + l15) * H_ + ((w + (i << 3)) << 5) + q8);
        if (b < 192) {
            const int yc = (b - 128) << 4;
#pragma unroll
            for (int i = 0; i < 8; ++i)
                pbB[i] = *(const bf16x8*)(WhqT + (size_t)(yc + l15) * H_ + ((w + (i << 3)) << 5) + q8);
        }
    }

    // ---------------- main recurrence --------------------------------------
    for (int t = 0; t < T_; ++t) {
        const int cur = t & 1, nxt = cur ^ 1;
        const __bf16* Xc = Xbf + (size_t)cur * B_ * I_;
        const __bf16* Hc = Hbf + (size_t)cur * B_ * H_;
        float o2[2];

        // ---- phase A: Z (blocks 0..127) / R,RH (blocks 128..255) ----
        if (b < 128) {
            gemm_reg<4, 8>(Xc, Hc, pbA, red, o2);
            zreg[0] = fsigmoid(o2[0] + bz[c16 + gc]);
            zreg[1] = fsigmoid(o2[1] + bz[c16 + gc + 1]);
        } else {
            gemm_reg<4, 8>(Xc, Hc, pbA, red, o2);
            bf16x2 h2 = *(const bf16x2*)(Hc + (size_t)gr * H_ + c16 + gc);
            float rh0 = fsigmoid(o2[0] + br[c16 + gc])     * (float)h2[0];
            float rh1 = fsigmoid(o2[1] + br[c16 + gc + 1]) * (float)h2[1];
            cstore4(RHbf + (size_t)gr * H_ + c16 + gc, pack2bf(rh0, rh1));
        }
        bar_arrive(arr);

        // ---- overlapped with barrier-1 wait (no dependency on RH) ----
        f32x4 accB[4];
#pragma unroll
        for (int m = 0; m < 4; ++m) accB[m] = f32x4{0.f, 0.f, 0.f, 0.f};
        if (b < 128) {
            // X-part of the H~ GEMM: depends only on Xc (already published)
            gemm_accN<4, 0>(Xc, I_, pbB, accB);
        } else if (b < 192) {
            // entire Y_{t-1} GEMM: depends only on Hc (already published)
            if (t > 0) {
                const int yc = (b - 128) << 4;
                gemm_accN<8, 0>(Hc, H_, pbB, accB);
                gemm_reduce(accB, red, o2);
                f32x2 v;
                v[0] = o2[0] + bhq[yc + gc];
                v[1] = o2[1] + bhq[yc + gc + 1];
                *(f32x2*)(out + ((size_t)(t - 1) * B_ + gr) * I_ + yc + gc) = v;
            }
        } else {
            // X_{t+1} conversion: depends only on global inputs
            if (t + 1 < T_ && tid < 256) {
                const int idx = (((b - 192) << 8) + tid) << 2;
                f32x4 v = *(const f32x4*)(inputs + (size_t)(t + 1) * B_ * I_ + idx);
                cstore8(Xbf + (size_t)nxt * B_ * I_ + idx,
                        pack4bf(v[0], v[1], v[2], v[3]));
            }
        }
        bar_wait(arr, epw, ++ep);

        // ---- phase B completion: H-part of H~, then H_new ----
        if (b < 128) {
            gemm_accN<8, 4>(RHbf, H_, pbB, accB);
            gemm_reduce(accB, red, o2);
            float ht0 = ftanh(o2[0] + bh[c16 + gc]);
            float ht1 = ftanh(o2[1] + bh[c16 + gc + 1]);
            float hn0 = zreg[0] * hreg[0] + (1.0f - zreg[0]) * ht0;
            float hn1 = zreg[1] * hreg[1] + (1.0f - zreg[1]) * ht1;
            hreg[0] = hn0; hreg[1] = hn1;
            cstore4(Hbf + (size_t)nxt * B_ * H_ + (size_t)gr * H_ + c16 + gc,
                    pack2bf(hn0, hn1));
            if (t == T_ - 1) {
                f32x2 v; v[0] = hn0; v[1] = hn1;
                *(f32x2*)(out + (size_t)T_ * B_ * I_ + (size_t)gr * H_ + c16 + gc) = v;
            }
        }
        bar_arrive(arr);
        bar_wait(arr, epw, ++ep);
    }

    // ---------------- epilogue: Y_{T-1} ------------------------------------
    if (b >= 128 && b < 192) {
        const __bf16* Hc = Hbf;   // slot (T_ & 1) == 0
        const int yc = (b - 128) << 4;
        f32x4 accB[4];
#pragma unroll
        for (int m = 0; m < 4; ++m) accB[m] = f32x4{0.f, 0.f, 0.f, 0.f};
        float o2[2];
        gemm_accN<8, 0>(Hc, H_, pbB, accB);
        gemm_reduce(accB, red, o2);
        f32x2 v;
        v[0] = o2[0] + bhq[yc + gc];
        v[1] = o2[1] + bhq[yc + gc + 1];
        *(f32x2*)(out + ((size_t)(T_ - 1) * B_ + gr) * I_ + yc + gc) = v;
    }
}

extern "C" void kernel_launch(void* const* d_in, const int* in_sizes, int n_in,
                              void* d_out, int out_size, void* d_ws, size_t ws_size,
                              hipStream_t stream) {
    if (ws_size < WS_NEEDED) return;  // ~41.5 MB scratch required

    const float* inputs = (const float*)d_in[0];
    const float* state  = (const float*)d_in[1];
    const float* Wxz    = (const float*)d_in[2];
    const float* Whz    = (const float*)d_in[3];
    const float* bz     = (const float*)d_in[4];
    const float* Wxr    = (const float*)d_in[5];
    const float* Whr    = (const float*)d_in[6];
    const float* br     = (const float*)d_in[7];
    const float* Wxh    = (const float*)d_in[8];
    const float* Whh    = (const float*)d_in[9];
    const float* bh     = (const float*)d_in[10];
    const float* Whq    = (const float*)d_in[11];
    const float* bhq    = (const float*)d_in[12];

    hipMemsetAsync(d_ws, 0, 2048, stream);  // arrival counters + epoch word
    gru_persistent<<<NB, NTHREADS, 0, stream>>>(
        inputs, state, Wxz, Whz, bz, Wxr, Whr, br, Wxh, Whh, bh, Whq, bhq,
        (float*)d_out, (char*)d_ws);
}